// Round 6
// baseline (314.407 us; speedup 1.0000x reference)
//
#include <hip/hip_runtime.h>
#include <hip/hip_bf16.h>

typedef unsigned short u16;
typedef __attribute__((ext_vector_type(8))) short bf16x8;
typedef __attribute__((ext_vector_type(4))) float f32x4;

#define GLDS16(g, l)                                                        \
  __builtin_amdgcn_global_load_lds(                                         \
      (const __attribute__((address_space(1))) void*)(g),                   \
      (__attribute__((address_space(3))) void*)(l), 16, 0, 0)

__device__ __forceinline__ u16 f2bf(float f) {
  union { float f; unsigned u; } v; v.f = f;
  unsigned r = v.u + 0x7FFFu + ((v.u >> 16) & 1u);
  return (u16)(r >> 16);
}

// ---------------- fused f32 -> bf16 conversion for all 7 inputs ----------
// blocks: [0,4096) key, [4096,8192) query, [8192,12288) value,
//         [12288,13312) Wk, [13312,14336) Wq, [14336,15360) Wv, [15360,16384) Wo
__global__ __launch_bounds__(256) void cvt_all(
    const float4* __restrict__ a0, const float4* __restrict__ a1,
    const float4* __restrict__ a2, const float4* __restrict__ a3,
    const float4* __restrict__ a4, const float4* __restrict__ a5,
    const float4* __restrict__ a6, ushort4* __restrict__ b0,
    ushort4* __restrict__ b1, ushort4* __restrict__ b2,
    ushort4* __restrict__ b3, ushort4* __restrict__ b4,
    ushort4* __restrict__ b5, ushort4* __restrict__ b6) {
  int bid = blockIdx.x;
  const float4* s; ushort4* d; int off;
  if (bid < 4096)       { s = a0; d = b0; off = bid; }
  else if (bid < 8192)  { s = a1; d = b1; off = bid - 4096; }
  else if (bid < 12288) { s = a2; d = b2; off = bid - 8192; }
  else if (bid < 13312) { s = a3; d = b3; off = bid - 12288; }
  else if (bid < 14336) { s = a4; d = b4; off = bid - 13312; }
  else if (bid < 15360) { s = a5; d = b5; off = bid - 14336; }
  else                  { s = a6; d = b6; off = bid - 15360; }
  int i = off * 256 + threadIdx.x;
  float4 v = s[i];
  ushort4 o;
  o.x = f2bf(v.x); o.y = f2bf(v.y); o.z = f2bf(v.z); o.w = f2bf(v.w);
  d[i] = o;
}

// ---------------- NT GEMM core: C[m,n] = sum_k A[m,k] * W[n,k] -----------
template <int MODE>
__device__ __forceinline__ void gemm_core(const u16* __restrict__ A,
                                          const u16* __restrict__ W,
                                          void* __restrict__ C) {
  const int K = 1024;
  __shared__ u16 lds_a[4096];  // 128 rows x 32 cols bf16 (64 B/row)
  __shared__ u16 lds_b[4096];
  const int bn = blockIdx.x, bm = blockIdx.y;
  const int tid = threadIdx.x, l = tid & 63, wid = tid >> 6;
  const int wr = wid >> 1, wc = wid & 1;
  const int l4 = l >> 4, l15 = l & 15;

  f32x4 zero4 = {0.f, 0.f, 0.f, 0.f};
  f32x4 acc[4][4];
  for (int i = 0; i < 4; ++i)
    for (int j = 0; j < 4; ++j) acc[i][j] = zero4;

  const int srow = tid >> 2, scol = (tid & 3) * 8;
  const u16* Ag = A + (bm * 128 + srow) * K + scol;
  const u16* Wg = W + (bn * 128 + srow) * K + scol;
  char* la = (char*)lds_a + wid * 1024;
  char* lb = (char*)lds_b + wid * 1024;

  for (int kt = 0; kt < K; kt += 32) {
    GLDS16(Ag + kt, la);
    GLDS16(Ag + 64 * K + kt, la + 4096);
    GLDS16(Wg + kt, lb);
    GLDS16(Wg + 64 * K + kt, lb + 4096);
    __syncthreads();
    bf16x8 af[4], bf[4];
    for (int i = 0; i < 4; ++i)
      af[i] = *(const bf16x8*)((const char*)lds_a +
                               (wr * 64 + i * 16 + l15) * 64 + l4 * 16);
    for (int j = 0; j < 4; ++j)
      bf[j] = *(const bf16x8*)((const char*)lds_b +
                               (wc * 64 + j * 16 + l15) * 64 + l4 * 16);
    for (int i = 0; i < 4; ++i)
      for (int j = 0; j < 4; ++j)
        acc[i][j] = __builtin_amdgcn_mfma_f32_16x16x32_bf16(af[i], bf[j],
                                                            acc[i][j], 0, 0, 0);
    __syncthreads();
  }

  for (int i = 0; i < 4; ++i)
    for (int j = 0; j < 4; ++j) {
      f32x4 a = acc[i][j];
      for (int r = 0; r < 4; ++r) {
        int m = bm * 128 + wr * 64 + i * 16 + l4 * 4 + r;
        int n = bn * 128 + wc * 64 + j * 16 + l15;
        if (MODE == 0) {
          int bb = m >> 11, srw = m & 2047, h = n >> 6, d = n & 63;
          ((u16*)C)[((bb * 16 + h) * 2048 + srw) * 64 + d] = f2bf(a[r]);
        } else {
          ((float*)C)[m * 1024 + n] = a[r];
        }
      }
    }
}

__global__ __launch_bounds__(256) void gemm_proj(
    const u16* __restrict__ X0, const u16* __restrict__ X1,
    const u16* __restrict__ X2, const u16* __restrict__ W0,
    const u16* __restrict__ W1, const u16* __restrict__ W2,
    u16* __restrict__ O0, u16* __restrict__ O1, u16* __restrict__ O2) {
  int z = blockIdx.z;
  const u16* A = (z == 0) ? X0 : (z == 1) ? X1 : X2;
  const u16* W = (z == 0) ? W0 : (z == 1) ? W1 : W2;
  u16* O = (z == 0) ? O0 : (z == 1) ? O1 : O2;
  gemm_core<0>(A, W, (void*)O);
}

__global__ __launch_bounds__(256) void gemm_out(const u16* __restrict__ A,
                                                const u16* __restrict__ W,
                                                float* __restrict__ C) {
  gemm_core<1>(A, W, (void*)C);
}

// ---------------- V (B,H,S,D) -> V^T (B,H,D,S) ---------------------------
__global__ __launch_bounds__(256) void transpose_v(const u16* __restrict__ Vp,
                                                   u16* __restrict__ Vt) {
  const int st = blockIdx.x, bh = blockIdx.y;
  const int d = threadIdx.x & 63, sg = threadIdx.x >> 6;
  const u16* src = Vp + bh * 131072;
  u16* dst = Vt + bh * 131072;
  const int s0 = st * 64 + sg * 16;
  u16 tmp[16];
  for (int i = 0; i < 16; ++i) tmp[i] = src[(s0 + i) * 64 + d];
  ushort4* o = (ushort4*)(dst + d * 2048 + s0);
  for (int k = 0; k < 4; ++k) {
    ushort4 t4;
    t4.x = tmp[4 * k]; t4.y = tmp[4 * k + 1];
    t4.z = tmp[4 * k + 2]; t4.w = tmp[4 * k + 3];
    o[k] = t4;
  }
}

// ---------------- causal flash attention --------------------------------
// Swapped-QK in-lane softmax; balanced q-tile pairs (x, 31-x) -> 33 iters
// per wave; XCD swizzle (each XCD owns 4 whole heads -> K/V L2-resident);
// register-double-buffered K/V prefetch (next tile's loads issued before
// current tile's compute). 1-D grid of 512 blocks.
__global__ __launch_bounds__(256, 2) void attn_kernel(
    const u16* __restrict__ Qp, const u16* __restrict__ Kp,
    const u16* __restrict__ Vt, u16* __restrict__ ctx) {
  const int bid = blockIdx.x;
  // XCD swizzle: dispatch is round-robin over 8 XCDs; give XCD c the
  // contiguous logical range [c*64, c*64+64) = heads 4c..4c+3 entirely.
  const int logical = ((bid & 7) << 6) | (bid >> 3);
  const int x = logical & 15, bh = logical >> 4;
  const int tid = threadIdx.x, w = tid >> 6, l = tid & 63;
  const int l4 = l >> 4, l15 = l & 15;
  __shared__ u16 lds_p[4][1024];  // per-wave 16x64 bf16 P tile, swizzled
  char* pw = (char*)lds_p[w];

  const u16* Qbh = Qp + bh * 131072;   // (S, 64)
  const u16* Kbh = Kp + bh * 131072;   // (S, 64)
  const u16* Vbh = Vt + bh * 131072;   // (64, S)
  const int b = bh >> 4, h = bh & 15;
  u16* ctxb = ctx + (size_t)b * 2048 * 1024 + h * 64;

  const float SCALE2 = 0.03125f * 1.44269504f;  // 1/32 * log2(e)
  const float PEN2 = 144269.5f;                 // 100000 * log2(e)
  const int swz = (l15 & 7) << 4;

  auto LOADK = [&](bf16x8* kf, int t) {
    const u16* kb = Kbh + (t * 64 + l15) * 64 + l4 * 8;
    for (int g = 0; g < 4; ++g) {
      kf[g] = *(const bf16x8*)(kb + g * 1024);
      kf[g + 4] = *(const bf16x8*)(kb + g * 1024 + 32);
    }
  };
  auto LOADV = [&](bf16x8* vf, int t) {
    const u16* vb = Vbh + l15 * 2048 + t * 64 + l4 * 8;
    for (int g = 0; g < 4; ++g) {
      vf[g] = *(const bf16x8*)(vb + g * 16 * 2048);
      vf[g + 4] = *(const bf16x8*)(vb + g * 16 * 2048 + 32);
    }
  };

  for (int half = 0; half < 2; ++half) {
    const int qt = half ? (31 - x) : x;
    const int q0 = qt * 64 + w * 16;

    // Q fragments (B-operand): Q[q0+l15][l4*8 + j], both 32-halves of D=64
    const u16* qb = Qbh + (q0 + l15) * 64 + l4 * 8;
    const bf16x8 bq0 = *(const bf16x8*)(qb);
    const bf16x8 bq1 = *(const bf16x8*)(qb + 32);

    f32x4 zero4 = {0.f, 0.f, 0.f, 0.f};
    f32x4 accO[4];
    for (int g = 0; g < 4; ++g) accO[g] = zero4;
    float m2 = -1.0e30f, lsum = 0.f;

    auto BODY = [&](const bf16x8* kf, const bf16x8* vf, int t2) {
      const int kv0 = t2 * 64;
      // ---- QK^T (swapped: lane column = q, regs = kv) ----
      f32x4 s[4];
      for (int g = 0; g < 4; ++g)
        s[g] = __builtin_amdgcn_mfma_f32_16x16x32_bf16(kf[g], bq0, zero4,
                                                       0, 0, 0);
      for (int g = 0; g < 4; ++g)
        s[g] = __builtin_amdgcn_mfma_f32_16x16x32_bf16(kf[g + 4], bq1, s[g],
                                                       0, 0, 0);
      // ---- scale (+ causal mask on diagonal tile), base-2 domain ----
      float sv[4][4];
      if (t2 == qt) {
        const int q = q0 + l15;
        for (int g = 0; g < 4; ++g)
          for (int r = 0; r < 4; ++r) {
            int kv = kv0 + g * 16 + l4 * 4 + r;
            sv[g][r] = s[g][r] * SCALE2 - (kv > q ? PEN2 : 0.f);
          }
      } else {
        for (int g = 0; g < 4; ++g)
          for (int r = 0; r < 4; ++r) sv[g][r] = s[g][r] * SCALE2;
      }
      // ---- in-lane tile max + 4-lane column reduce ----
      float mx = sv[0][0];
      for (int g = 0; g < 4; ++g)
        for (int r = 0; r < 4; ++r) mx = fmaxf(mx, sv[g][r]);
      mx = fmaxf(mx, __shfl_xor(mx, 16));
      mx = fmaxf(mx, __shfl_xor(mx, 32));
      const float mnew = fmaxf(m2, mx);
      const float alpha = __builtin_exp2f(m2 - mnew);
      m2 = mnew;
      // ---- p = 2^(s-m), row sum ----
      float p[4][4], rs = 0.f;
      for (int g = 0; g < 4; ++g)
        for (int r = 0; r < 4; ++r) {
          float e = __builtin_exp2f(sv[g][r] - mnew);
          p[g][r] = e;
          rs += e;
        }
      rs += __shfl_xor(rs, 16);
      rs += __shfl_xor(rs, 32);
      lsum = lsum * alpha + rs;
      // ---- rescale accO (alpha for q-row l4*4+r lives in lane l4*4+r) ----
      float aR[4];
      for (int r = 0; r < 4; ++r) aR[r] = __shfl(alpha, l4 * 4 + r);
      for (int g = 0; g < 4; ++g) {
        f32x4 t = accO[g];
        t[0] *= aR[0]; t[1] *= aR[1]; t[2] *= aR[2]; t[3] *= aR[3];
        accO[g] = t;
      }
      // ---- P -> bf16 -> LDS (4x ds_write_b64, XOR-swizzled rows) ----
      for (int g = 0; g < 4; ++g) {
        ushort4 q4;
        q4.x = f2bf(p[g][0]); q4.y = f2bf(p[g][1]);
        q4.z = f2bf(p[g][2]); q4.w = f2bf(p[g][3]);
        int byte = (l15 * 128 + g * 32 + l4 * 8) ^ swz;
        *(ushort4*)(pw + byte) = q4;
      }
      // ---- A-fragments of P (2x ds_read_b128) ----
      bf16x8 pa0 = *(const bf16x8*)(pw + ((l15 * 128 + l4 * 16) ^ swz));
      bf16x8 pa1 = *(const bf16x8*)(pw + ((l15 * 128 + 64 + l4 * 16) ^ swz));
      // ---- O += P V ----
      for (int g = 0; g < 4; ++g)
        accO[g] = __builtin_amdgcn_mfma_f32_16x16x32_bf16(pa0, vf[g],
                                                          accO[g], 0, 0, 0);
      for (int g = 0; g < 4; ++g)
        accO[g] = __builtin_amdgcn_mfma_f32_16x16x32_bf16(pa1, vf[g + 4],
                                                          accO[g], 0, 0, 0);
    };

    // ---- register-double-buffered K/V pipeline ----
    bf16x8 k0[8], v0[8], k1[8], v1[8];
    LOADK(k0, 0); LOADV(v0, 0);
    int t2 = 0;
    while (true) {
      if (t2 < qt) { LOADK(k1, t2 + 1); LOADV(v1, t2 + 1); }
      BODY(k0, v0, t2);
      if (++t2 > qt) break;
      if (t2 < qt) { LOADK(k0, t2 + 1); LOADV(v0, t2 + 1); }
      BODY(k1, v1, t2);
      if (++t2 > qt) break;
    }

    // ---- epilogue: broadcast 1/lsum to row holders, store ----
    float inv[4];
    for (int r = 0; r < 4; ++r) inv[r] = 1.f / __shfl(lsum, l4 * 4 + r);
    for (int r = 0; r < 4; ++r) {
      u16* orow = ctxb + (size_t)(q0 + l4 * 4 + r) * 1024;
      for (int g = 0; g < 4; ++g)
        orow[g * 16 + l15] = f2bf(accO[g][r] * inv[r]);
    }
  }
}

extern "C" void kernel_launch(void* const* d_in, const int* in_sizes, int n_in,
                              void* d_out, int out_size, void* d_ws,
                              size_t ws_size, hipStream_t stream) {
  (void)in_sizes; (void)n_in; (void)out_size; (void)ws_size;
  const float* key = (const float*)d_in[0];
  const float* query = (const float*)d_in[1];
  const float* value = (const float*)d_in[2];
  const float* Wk = (const float*)d_in[3];
  const float* Wq = (const float*)d_in[4];
  const float* Wv = (const float*)d_in[5];
  const float* Wo = (const float*)d_in[6];

  char* ws = (char*)d_ws;
  u16* keyb = (u16*)(ws + 0);          // 4096x1024 bf16
  u16* qryb = (u16*)(ws + 8388608);
  u16* valb = (u16*)(ws + 16777216);
  u16* Wkb  = (u16*)(ws + 25165824);   // 1024x1024 bf16 each
  u16* Wqb  = (u16*)(ws + 27262976);
  u16* Wvb  = (u16*)(ws + 29360128);
  u16* Wob  = (u16*)(ws + 31457280);
  u16* Kp   = (u16*)(ws + 33554432);   // (B,H,S,D) bf16
  u16* Qp   = (u16*)(ws + 41943040);
  u16* Vp   = (u16*)(ws + 50331648);
  u16* Vt   = (u16*)(ws + 58720256);   // (B,H,D,S) bf16
  u16* ctx  = (u16*)(ws + 67108864);   // (B*S, 1024) bf16

  cvt_all<<<16384, 256, 0, stream>>>(
      (const float4*)key, (const float4*)query, (const float4*)value,
      (const float4*)Wk, (const float4*)Wq, (const float4*)Wv,
      (const float4*)Wo, (ushort4*)keyb, (ushort4*)qryb, (ushort4*)valb,
      (ushort4*)Wkb, (ushort4*)Wqb, (ushort4*)Wvb, (ushort4*)Wob);

  gemm_proj<<<dim3(8, 32, 3), 256, 0, stream>>>(keyb, qryb, valb, Wkb, Wqb,
                                                Wvb, Kp, Qp, Vp);
  transpose_v<<<dim3(32, 32), 256, 0, stream>>>(Vp, Vt);
  attn_kernel<<<512, 256, 0, stream>>>(Qp, Kp, Vt, ctx);
  gemm_out<<<dim3(8, 32), 256, 0, stream>>>(ctx, Wob, (float*)d_out);
}